// Round 18
// baseline (167.725 us; speedup 1.0000x reference)
//
#include <hip/hip_runtime.h>
#include <hip/hip_bf16.h>

typedef __attribute__((ext_vector_type(8))) short short8;
typedef __attribute__((ext_vector_type(8))) unsigned short ushort8;
typedef __attribute__((ext_vector_type(4))) float floatx4;

#define L2E 1.4426950408889634f

#if __has_builtin(__builtin_amdgcn_exp2f)
#define EXP2(x) __builtin_amdgcn_exp2f(x)
#else
#define EXP2(x) exp2f(x)
#endif
#if __has_builtin(__builtin_amdgcn_rcpf)
#define RCP(x) __builtin_amdgcn_rcpf(x)
#else
#define RCP(x) (1.0f / (x))
#endif

static __device__ __forceinline__ unsigned short f2bf(float f) {
    unsigned int u = __builtin_bit_cast(unsigned int, f);
    u += 0x7fffu + ((u >> 16) & 1u);   // RNE
    return (unsigned short)(u >> 16);
}
static __device__ __forceinline__ unsigned int pk_bf16(float a, float b) {
    __hip_bfloat162 h2 = __float22bfloat162_rn(make_float2(a, b));   // v_cvt_pk_bf16_f32
    unsigned int u;
    __builtin_memcpy(&u, &h2, 4);     // low16 = a, high16 = b
    return u;
}

// ---------------- 1) QKV GEMM, self-staging; At stage vectorized (4c x 4m -> b64 writes) ----------------
__global__ __launch_bounds__(256) void k_qkv(const float* __restrict__ x,
                                             const float* __restrict__ qw,
                                             unsigned short* __restrict__ qm,
                                             unsigned short* __restrict__ km,
                                             unsigned short* __restrict__ vt) {
    __shared__ __align__(16) unsigned short At[64][136];
    __shared__ __align__(16) unsigned short Wt[64][136];
    const int tid = threadIdx.x;
    const int wave = tid >> 6, lane = tid & 63;
    const int l16 = lane & 15, quad = lane >> 4;
    const int m0 = blockIdx.x * 64;
    const int o0 = blockIdx.y * 64;

    floatx4 acc[4] = {};
    for (int rnd = 0; rnd < 2; ++rnd) {
        const int cbase = rnd * 128;
        if (rnd) __syncthreads();
        // stage A (transposed, packed): 512 groups of 4c x 4m; 8 b64 LDS writes/thread
        {
            #pragma unroll
            for (int g = 0; g < 2; ++g) {
                const int G = tid + g * 256;
                const int c4 = (G & 31) * 4;
                const int mg = (G >> 5) * 4;
                const float* xp = x + (size_t)(cbase + c4) * 4096 + m0 + mg;
                const float4 r0 = *reinterpret_cast<const float4*>(xp);
                const float4 r1 = *reinterpret_cast<const float4*>(xp + 4096);
                const float4 r2 = *reinterpret_cast<const float4*>(xp + 8192);
                const float4 r3 = *reinterpret_cast<const float4*>(xp + 12288);
                unsigned int w0[2] = {pk_bf16(r0.x, r1.x), pk_bf16(r2.x, r3.x)};
                __builtin_memcpy(&At[mg + 0][c4], w0, 8);
                unsigned int w1[2] = {pk_bf16(r0.y, r1.y), pk_bf16(r2.y, r3.y)};
                __builtin_memcpy(&At[mg + 1][c4], w1, 8);
                unsigned int w2[2] = {pk_bf16(r0.z, r1.z), pk_bf16(r2.z, r3.z)};
                __builtin_memcpy(&At[mg + 2][c4], w2, 8);
                unsigned int w3[2] = {pk_bf16(r0.w, r1.w), pk_bf16(r2.w, r3.w)};
                __builtin_memcpy(&At[mg + 3][c4], w3, 8);
            }
        }
        // stage W (row-major, b128 writes)
        {
            const int o_l = tid >> 2, cp = (tid & 3) * 32;
            const float4* wp = reinterpret_cast<const float4*>(
                qw + (size_t)(o0 + o_l) * 256 + cbase + cp);
            #pragma unroll
            for (int j = 0; j < 2; ++j) {
                const float4 g0 = wp[4 * j + 0], g1 = wp[4 * j + 1];
                const float4 g2 = wp[4 * j + 2], g3 = wp[4 * j + 3];
                unsigned int u[8];
                u[0] = pk_bf16(g0.x, g0.y); u[1] = pk_bf16(g0.z, g0.w);
                u[2] = pk_bf16(g1.x, g1.y); u[3] = pk_bf16(g1.z, g1.w);
                u[4] = pk_bf16(g2.x, g2.y); u[5] = pk_bf16(g2.z, g2.w);
                u[6] = pk_bf16(g3.x, g3.y); u[7] = pk_bf16(g3.z, g3.w);
                __builtin_memcpy(&Wt[o_l][cp + 16 * j], u, 32);
            }
        }
        __syncthreads();
        #pragma unroll
        for (int cc = 0; cc < 4; ++cc) {
            const int c0 = cc * 32 + quad * 8;
            const short8 a = *reinterpret_cast<const short8*>(&At[wave * 16 + l16][c0]);
            #pragma unroll
            for (int t4 = 0; t4 < 4; ++t4) {
                const short8 b = *reinterpret_cast<const short8*>(&Wt[t4 * 16 + l16][c0]);
                acc[t4] = __builtin_amdgcn_mfma_f32_16x16x32_bf16(a, b, acc[t4], 0, 0, 0);
            }
        }
    }
    const float qscale = 0.17677669529663687f * L2E;
    #pragma unroll
    for (int t4 = 0; t4 < 4; ++t4) {
        #pragma unroll
        for (int r = 0; r < 4; ++r) {
            const int n = m0 + wave * 16 + quad * 4 + r;
            const int o = o0 + t4 * 16 + l16;
            const int s = o >> 8, rem = o & 255, head = rem >> 5, t = rem & 31;
            if (s == 0)       qm[((size_t)head * 4096 + n) * 32 + t] = f2bf(acc[t4][r] * qscale);
            else if (s == 1)  km[((size_t)head * 4096 + n) * 32 + t] = f2bf(acc[t4][r]);
            else              vt[((size_t)head * 32 + t) * 4096 + n] = f2bf(acc[t4][r]);
        }
    }
}

// ---------------- 2) flash attention: R17 pipeline + load-balancing block swizzle ----------------
__global__ __launch_bounds__(256) void k_attn(const unsigned short* __restrict__ qm,
                                              const unsigned short* __restrict__ km,
                                              const unsigned short* __restrict__ vt,
                                              unsigned short* __restrict__ ao) {
    const int h   = blockIdx.y;
    const int qt  = (blockIdx.x * 149) & 255;   // odd-multiplier permutation: decorrelates d
    const int nq0 = qt * 16;                    // across consecutive blocks -> per-CU balance
    const int tid = threadIdx.x;
    const int wv  = __builtin_amdgcn_readfirstlane(tid >> 6);   // scalar: scan stays SALU
    const int lane = tid & 63;
    const int l16 = lane & 15, quad = lane >> 4;

    __shared__ __align__(16) char smem[4][4608];
    typedef unsigned short ptrow_t[16][72];   // one PT buffer: 16 q-rows x 72 (2304 B)
    ptrow_t* PTw = reinterpret_cast<ptrow_t*>(smem[wv]);        // PTw[buf][q][key]

    const short8 a_q = *reinterpret_cast<const short8*>(
        qm + ((size_t)h * 4096 + nq0 + l16) * 32 + quad * 8);

    const int hq = (nq0 >> 4) & 15, dq = nq0 >> 8;
    float dw2[4];
    #pragma unroll
    for (int r = 0; r < 4; ++r) {
        const float dw = (float)(quad * 4 + r - l16);   // key_w - q_w (symmetric form)
        dw2[r] = dw * dw;
    }

    const unsigned short* kmh = km + ((size_t)h << 17) + l16 * 32 + quad * 8;
    const unsigned short* vt0 = vt + ((size_t)(h * 32 + l16) << 12) + quad * 8;
    const unsigned short* vt1 = vt0 + (16 << 12);

    float l_acc = 0.f;
    floatx4 o_acc[2] = {};

    int jt = -1, c = 0;

#define SCAN(J0, THR)                                                     \
    J0 = -1;                                                              \
    while (++jt < 64) {                                                   \
        const int dk = jt >> 2, hk0 = (jt & 3) * 4;                       \
        const int dd = dq - dk;                                           \
        int dh = 0;                                                       \
        if (hq < hk0) dh = hk0 - hq;                                      \
        else if (hq > hk0 + 3) dh = hq - hk0 - 3;                         \
        if (dd * dd + dh * dh >= 100) continue;                           \
        if (((c++) & 3) != wv) continue;                                  \
        J0 = jt * 64;                                                     \
        const int bb = 100 - dd * dd;                                     \
        THR[0] = bb - (hq - hk0) * (hq - hk0);                            \
        THR[1] = bb - (hq - hk0 - 1) * (hq - hk0 - 1);                    \
        THR[2] = bb - (hq - hk0 - 2) * (hq - hk0 - 2);                    \
        THR[3] = bb - (hq - hk0 - 3) * (hq - hk0 - 3);                    \
        break;                                                            \
    }

#define SSTAGE(THR, KB, BUF)                                              \
    {                                                                     \
        _Pragma("unroll")                                                 \
        for (int t4 = 0; t4 < 4; ++t4) {                                  \
            const bool sib = (THR[t4 ^ 1] > 0);                           \
            if (THR[t4] > 0) {                                            \
                const floatx4 sf = __builtin_amdgcn_mfma_f32_16x16x32_bf16( \
                    KB[t4], a_q, (floatx4){0.f, 0.f, 0.f, 0.f}, 0, 0, 0); \
                const float thrf = (float)THR[t4];                        \
                const float p0 = (dw2[0] < thrf) ? EXP2(sf[0]) : 0.f;     \
                const float p1 = (dw2[1] < thrf) ? EXP2(sf[1]) : 0.f;     \
                const float p2 = (dw2[2] < thrf) ? EXP2(sf[2]) : 0.f;     \
                const float p3 = (dw2[3] < thrf) ? EXP2(sf[3]) : 0.f;     \
                l_acc += (p0 + p1) + (p2 + p3);                           \
                unsigned int pair[2];                                     \
                pair[0] = pk_bf16(p0, p1);                                \
                pair[1] = pk_bf16(p2, p3);                                \
                __builtin_memcpy(&PTw[BUF][l16][t4 * 16 + quad * 4], pair, 8); \
            } else if (sib) {                                             \
                const unsigned int zz[2] = {0u, 0u};                      \
                __builtin_memcpy(&PTw[BUF][l16][t4 * 16 + quad * 4], zz, 8); \
            }                                                             \
        }                                                                 \
    }

    // ---- prologue ----
    int j0p, thrp[4];
    SCAN(j0p, thrp)
    if (j0p >= 0) {
        short8 kprev[4];
        #pragma unroll
        for (int t4 = 0; t4 < 4; ++t4)
            kprev[t4] = *reinterpret_cast<const short8*>(kmh + ((j0p + t4 * 16) << 5));
        SSTAGE(thrp, kprev, 0)
    }

    int j0c, thrc[4];
    SCAN(j0c, thrc)
    short8 kb[4];
    if (j0c >= 0) {
        #pragma unroll
        for (int t4 = 0; t4 < 4; ++t4)
            kb[t4] = *reinterpret_cast<const short8*>(kmh + ((j0c + t4 * 16) << 5));
    }

    int pb = 0;
    while (j0p >= 0) {
        const short8 v00 = *reinterpret_cast<const short8*>(vt0 + j0p);
        const short8 v01 = *reinterpret_cast<const short8*>(vt1 + j0p);
        const short8 v10 = *reinterpret_cast<const short8*>(vt0 + j0p + 32);
        const short8 v11 = *reinterpret_cast<const short8*>(vt1 + j0p + 32);

        if (j0c >= 0) SSTAGE(thrc, kb, pb ^ 1)

        int j0n, thrn[4];
        SCAN(j0n, thrn)
        short8 kn[4];
        if (j0n >= 0) {
            #pragma unroll
            for (int t4 = 0; t4 < 4; ++t4)
                kn[t4] = *reinterpret_cast<const short8*>(kmh + ((j0n + t4 * 16) << 5));
        }

        #pragma unroll
        for (int kt = 0; kt < 2; ++kt) {
            if (thrp[2 * kt] <= 0 && thrp[2 * kt + 1] <= 0) continue;
            const short8 b_p = *reinterpret_cast<const short8*>(
                &PTw[pb][l16][kt * 32 + quad * 8]);
            o_acc[0] = __builtin_amdgcn_mfma_f32_16x16x32_bf16(
                kt ? v10 : v00, b_p, o_acc[0], 0, 0, 0);
            o_acc[1] = __builtin_amdgcn_mfma_f32_16x16x32_bf16(
                kt ? v11 : v01, b_p, o_acc[1], 0, 0, 0);
        }

        j0p = j0c;
        #pragma unroll
        for (int t4 = 0; t4 < 4; ++t4) { thrp[t4] = thrc[t4]; kb[t4] = kn[t4]; thrc[t4] = thrn[t4]; }
        j0c = j0n;
        pb ^= 1;
    }
#undef SSTAGE
#undef SCAN

    // ---- epilogue: reuse this wave's smem region for O/l partials ----
    float (*obufw)[20] = reinterpret_cast<float(*)[20]>(smem[wv]);   // [32][20]
    float* lbufw = reinterpret_cast<float*>(smem[wv] + 2560);        // [16]

    l_acc += __shfl_xor(l_acc, 16);
    l_acc += __shfl_xor(l_acc, 32);
    if (lane < 16) lbufw[l16] = l_acc;
    #pragma unroll
    for (int tt = 0; tt < 2; ++tt)
        #pragma unroll
        for (int r = 0; r < 4; ++r)
            obufw[tt * 16 + quad * 4 + r][l16] = o_acc[tt][r];
    __syncthreads();

    const int q = tid & 15, d0 = (tid >> 4) * 2;
    float lt = 0.f, oa = 0.f, ob = 0.f;
    #pragma unroll
    for (int w = 0; w < 4; ++w) {
        const float (*obw)[20] = reinterpret_cast<const float(*)[20]>(smem[w]);
        lt += reinterpret_cast<const float*>(smem[w] + 2560)[q];
        oa += obw[d0][q];
        ob += obw[d0 + 1][q];
    }
    const float inv = RCP(lt);
    const unsigned int uo = pk_bf16(oa * inv, ob * inv);
    *reinterpret_cast<unsigned int*>(ao + (size_t)(nq0 + q) * 256 + h * 32 + d0) = uo;
}

// ---------------- 3) proj GEMM + bias, self-staging pw (unchanged) ----------------
__global__ __launch_bounds__(256) void k_proj(const unsigned short* __restrict__ ao,
                                              const float* __restrict__ pw,
                                              const float* __restrict__ pb,
                                              float* __restrict__ out) {
    __shared__ __align__(16) unsigned short Pt[64][264];
    const int tid = threadIdx.x;
    const int wave = tid >> 6, lane = tid & 63;
    const int l16 = lane & 15, quad = lane >> 4;
    const int n0 = blockIdx.x * 64;
    const int m0 = blockIdx.y * 64;

    {
        const int o_l = tid >> 2, cp = (tid & 3) * 64;
        const float4* wp = reinterpret_cast<const float4*>(pw + (size_t)(m0 + o_l) * 256 + cp);
        #pragma unroll
        for (int j = 0; j < 4; ++j) {
            const float4 g0 = wp[4 * j + 0], g1 = wp[4 * j + 1];
            const float4 g2 = wp[4 * j + 2], g3 = wp[4 * j + 3];
            unsigned int u[8];
            u[0] = pk_bf16(g0.x, g0.y); u[1] = pk_bf16(g0.z, g0.w);
            u[2] = pk_bf16(g1.x, g1.y); u[3] = pk_bf16(g1.z, g1.w);
            u[4] = pk_bf16(g2.x, g2.y); u[5] = pk_bf16(g2.z, g2.w);
            u[6] = pk_bf16(g3.x, g3.y); u[7] = pk_bf16(g3.z, g3.w);
            __builtin_memcpy(&Pt[o_l][cp + 16 * j], u, 32);
        }
    }
    __syncthreads();

    floatx4 acc[4] = {};
    #pragma unroll
    for (int cc = 0; cc < 8; ++cc) {
        const int c0 = cc * 32 + quad * 8;
        const short8 a = *reinterpret_cast<const short8*>(&Pt[wave * 16 + l16][c0]);
        #pragma unroll
        for (int t4 = 0; t4 < 4; ++t4) {
            const short8 b = *reinterpret_cast<const short8*>(
                ao + (size_t)(n0 + t4 * 16 + l16) * 256 + c0);
            acc[t4] = __builtin_amdgcn_mfma_f32_16x16x32_bf16(a, b, acc[t4], 0, 0, 0);
        }
    }
    #pragma unroll
    for (int t4 = 0; t4 < 4; ++t4) {
        #pragma unroll
        for (int r = 0; r < 4; ++r) {
            const int o = m0 + wave * 16 + quad * 4 + r;
            const int n = n0 + t4 * 16 + l16;
            out[(size_t)o * 4096 + n] = acc[t4][r] + pb[o];
        }
    }
}

extern "C" void kernel_launch(void* const* d_in, const int* in_sizes, int n_in,
                              void* d_out, int out_size, void* d_ws, size_t ws_size,
                              hipStream_t stream) {
    const float* x      = (const float*)d_in[0];
    const float* qkv_w  = (const float*)d_in[1];
    const float* proj_w = (const float*)d_in[2];
    const float* proj_b = (const float*)d_in[3];
    float* out = (float*)d_out;                    // [256,4096] fp32

    char* B = (char*)d_ws;
    const size_t MB = 1u << 20;
    unsigned short* ao = (unsigned short*)(B);
    unsigned short* qm = (unsigned short*)(B + 2 * MB);
    unsigned short* km = (unsigned short*)(B + 4 * MB);
    unsigned short* vt = (unsigned short*)(B + 6 * MB);

    k_qkv<<<dim3(64, 12), 256, 0, stream>>>(x, qkv_w, qm, km, vt);
    k_attn<<<dim3(256, 8), 256, 0, stream>>>(qm, km, vt, ao);
    k_proj<<<dim3(64, 4), 256, 0, stream>>>(ao, proj_w, proj_b, out);
}

// Round 19
// 164.880 us; speedup vs baseline: 1.0173x; 1.0173x over previous
//
#include <hip/hip_runtime.h>
#include <hip/hip_bf16.h>

typedef __attribute__((ext_vector_type(8))) short short8;
typedef __attribute__((ext_vector_type(8))) unsigned short ushort8;
typedef __attribute__((ext_vector_type(4))) float floatx4;

#define L2E 1.4426950408889634f

#if __has_builtin(__builtin_amdgcn_exp2f)
#define EXP2(x) __builtin_amdgcn_exp2f(x)
#else
#define EXP2(x) exp2f(x)
#endif
#if __has_builtin(__builtin_amdgcn_rcpf)
#define RCP(x) __builtin_amdgcn_rcpf(x)
#else
#define RCP(x) (1.0f / (x))
#endif

static __device__ __forceinline__ unsigned short f2bf(float f) {
    unsigned int u = __builtin_bit_cast(unsigned int, f);
    u += 0x7fffu + ((u >> 16) & 1u);   // RNE
    return (unsigned short)(u >> 16);
}
static __device__ __forceinline__ unsigned int pk_bf16(float a, float b) {
    __hip_bfloat162 h2 = __float22bfloat162_rn(make_float2(a, b));   // v_cvt_pk_bf16_f32
    unsigned int u;
    __builtin_memcpy(&u, &h2, 4);     // low16 = a, high16 = b
    return u;
}

// ---------------- 1) QKV GEMM, self-staging (unchanged from R18) ----------------
__global__ __launch_bounds__(256) void k_qkv(const float* __restrict__ x,
                                             const float* __restrict__ qw,
                                             unsigned short* __restrict__ qm,
                                             unsigned short* __restrict__ km,
                                             unsigned short* __restrict__ vt) {
    __shared__ __align__(16) unsigned short At[64][136];
    __shared__ __align__(16) unsigned short Wt[64][136];
    const int tid = threadIdx.x;
    const int wave = tid >> 6, lane = tid & 63;
    const int l16 = lane & 15, quad = lane >> 4;
    const int m0 = blockIdx.x * 64;
    const int o0 = blockIdx.y * 64;

    floatx4 acc[4] = {};
    for (int rnd = 0; rnd < 2; ++rnd) {
        const int cbase = rnd * 128;
        if (rnd) __syncthreads();
        {
            #pragma unroll
            for (int g = 0; g < 2; ++g) {
                const int G = tid + g * 256;
                const int c4 = (G & 31) * 4;
                const int mg = (G >> 5) * 4;
                const float* xp = x + (size_t)(cbase + c4) * 4096 + m0 + mg;
                const float4 r0 = *reinterpret_cast<const float4*>(xp);
                const float4 r1 = *reinterpret_cast<const float4*>(xp + 4096);
                const float4 r2 = *reinterpret_cast<const float4*>(xp + 8192);
                const float4 r3 = *reinterpret_cast<const float4*>(xp + 12288);
                unsigned int w0[2] = {pk_bf16(r0.x, r1.x), pk_bf16(r2.x, r3.x)};
                __builtin_memcpy(&At[mg + 0][c4], w0, 8);
                unsigned int w1[2] = {pk_bf16(r0.y, r1.y), pk_bf16(r2.y, r3.y)};
                __builtin_memcpy(&At[mg + 1][c4], w1, 8);
                unsigned int w2[2] = {pk_bf16(r0.z, r1.z), pk_bf16(r2.z, r3.z)};
                __builtin_memcpy(&At[mg + 2][c4], w2, 8);
                unsigned int w3[2] = {pk_bf16(r0.w, r1.w), pk_bf16(r2.w, r3.w)};
                __builtin_memcpy(&At[mg + 3][c4], w3, 8);
            }
        }
        {
            const int o_l = tid >> 2, cp = (tid & 3) * 32;
            const float4* wp = reinterpret_cast<const float4*>(
                qw + (size_t)(o0 + o_l) * 256 + cbase + cp);
            #pragma unroll
            for (int j = 0; j < 2; ++j) {
                const float4 g0 = wp[4 * j + 0], g1 = wp[4 * j + 1];
                const float4 g2 = wp[4 * j + 2], g3 = wp[4 * j + 3];
                unsigned int u[8];
                u[0] = pk_bf16(g0.x, g0.y); u[1] = pk_bf16(g0.z, g0.w);
                u[2] = pk_bf16(g1.x, g1.y); u[3] = pk_bf16(g1.z, g1.w);
                u[4] = pk_bf16(g2.x, g2.y); u[5] = pk_bf16(g2.z, g2.w);
                u[6] = pk_bf16(g3.x, g3.y); u[7] = pk_bf16(g3.z, g3.w);
                __builtin_memcpy(&Wt[o_l][cp + 16 * j], u, 32);
            }
        }
        __syncthreads();
        #pragma unroll
        for (int cc = 0; cc < 4; ++cc) {
            const int c0 = cc * 32 + quad * 8;
            const short8 a = *reinterpret_cast<const short8*>(&At[wave * 16 + l16][c0]);
            #pragma unroll
            for (int t4 = 0; t4 < 4; ++t4) {
                const short8 b = *reinterpret_cast<const short8*>(&Wt[t4 * 16 + l16][c0]);
                acc[t4] = __builtin_amdgcn_mfma_f32_16x16x32_bf16(a, b, acc[t4], 0, 0, 0);
            }
        }
    }
    const float qscale = 0.17677669529663687f * L2E;
    #pragma unroll
    for (int t4 = 0; t4 < 4; ++t4) {
        #pragma unroll
        for (int r = 0; r < 4; ++r) {
            const int n = m0 + wave * 16 + quad * 4 + r;
            const int o = o0 + t4 * 16 + l16;
            const int s = o >> 8, rem = o & 255, head = rem >> 5, t = rem & 31;
            if (s == 0)       qm[((size_t)head * 4096 + n) * 32 + t] = f2bf(acc[t4][r] * qscale);
            else if (s == 1)  km[((size_t)head * 4096 + n) * 32 + t] = f2bf(acc[t4][r]);
            else              vt[((size_t)head * 32 + t) * 4096 + n] = f2bf(acc[t4][r]);
        }
    }
}

// ---------------- 2) flash attention: R18 pipeline + head-per-XCD mapping ----------------
// Flat grid 2048; h = blockIdx.x & 7 == XCD id (blockIdx round-robins XCDs), so each
// XCD touches only ONE head's q/k/v (768 KB << 4 MB L2) -> K/V loads L2-hot.
__global__ __launch_bounds__(256) void k_attn(const unsigned short* __restrict__ qm,
                                              const unsigned short* __restrict__ km,
                                              const unsigned short* __restrict__ vt,
                                              unsigned short* __restrict__ ao) {
    const int h   = blockIdx.x & 7;
    const int qt  = ((blockIdx.x >> 3) * 149) & 255;   // odd-mult permutation within head
    const int nq0 = qt * 16;
    const int tid = threadIdx.x;
    const int wv  = __builtin_amdgcn_readfirstlane(tid >> 6);
    const int lane = tid & 63;
    const int l16 = lane & 15, quad = lane >> 4;

    __shared__ __align__(16) char smem[4][4608];
    typedef unsigned short ptrow_t[16][72];
    ptrow_t* PTw = reinterpret_cast<ptrow_t*>(smem[wv]);

    const short8 a_q = *reinterpret_cast<const short8*>(
        qm + ((size_t)h * 4096 + nq0 + l16) * 32 + quad * 8);

    const int hq = (nq0 >> 4) & 15, dq = nq0 >> 8;
    float dw2[4];
    #pragma unroll
    for (int r = 0; r < 4; ++r) {
        const float dw = (float)(quad * 4 + r - l16);
        dw2[r] = dw * dw;
    }

    const unsigned short* kmh = km + ((size_t)h << 17) + l16 * 32 + quad * 8;
    const unsigned short* vt0 = vt + ((size_t)(h * 32 + l16) << 12) + quad * 8;
    const unsigned short* vt1 = vt0 + (16 << 12);

    float l_acc = 0.f;
    floatx4 o_acc[2] = {};

    int jt = -1, c = 0;

#define SCAN(J0, THR)                                                     \
    J0 = -1;                                                              \
    while (++jt < 64) {                                                   \
        const int dk = jt >> 2, hk0 = (jt & 3) * 4;                       \
        const int dd = dq - dk;                                           \
        int dh = 0;                                                       \
        if (hq < hk0) dh = hk0 - hq;                                      \
        else if (hq > hk0 + 3) dh = hq - hk0 - 3;                         \
        if (dd * dd + dh * dh >= 100) continue;                           \
        if (((c++) & 3) != wv) continue;                                  \
        J0 = jt * 64;                                                     \
        const int bb = 100 - dd * dd;                                     \
        THR[0] = bb - (hq - hk0) * (hq - hk0);                            \
        THR[1] = bb - (hq - hk0 - 1) * (hq - hk0 - 1);                    \
        THR[2] = bb - (hq - hk0 - 2) * (hq - hk0 - 2);                    \
        THR[3] = bb - (hq - hk0 - 3) * (hq - hk0 - 3);                    \
        break;                                                            \
    }

#define SSTAGE(THR, KB, BUF)                                              \
    {                                                                     \
        _Pragma("unroll")                                                 \
        for (int t4 = 0; t4 < 4; ++t4) {                                  \
            const bool sib = (THR[t4 ^ 1] > 0);                           \
            if (THR[t4] > 0) {                                            \
                const floatx4 sf = __builtin_amdgcn_mfma_f32_16x16x32_bf16( \
                    KB[t4], a_q, (floatx4){0.f, 0.f, 0.f, 0.f}, 0, 0, 0); \
                const float thrf = (float)THR[t4];                        \
                const float p0 = (dw2[0] < thrf) ? EXP2(sf[0]) : 0.f;     \
                const float p1 = (dw2[1] < thrf) ? EXP2(sf[1]) : 0.f;     \
                const float p2 = (dw2[2] < thrf) ? EXP2(sf[2]) : 0.f;     \
                const float p3 = (dw2[3] < thrf) ? EXP2(sf[3]) : 0.f;     \
                l_acc += (p0 + p1) + (p2 + p3);                           \
                unsigned int pair[2];                                     \
                pair[0] = pk_bf16(p0, p1);                                \
                pair[1] = pk_bf16(p2, p3);                                \
                __builtin_memcpy(&PTw[BUF][l16][t4 * 16 + quad * 4], pair, 8); \
            } else if (sib) {                                             \
                const unsigned int zz[2] = {0u, 0u};                      \
                __builtin_memcpy(&PTw[BUF][l16][t4 * 16 + quad * 4], zz, 8); \
            }                                                             \
        }                                                                 \
    }

    // ---- prologue ----
    int j0p, thrp[4];
    SCAN(j0p, thrp)
    if (j0p >= 0) {
        short8 kprev[4];
        #pragma unroll
        for (int t4 = 0; t4 < 4; ++t4)
            kprev[t4] = *reinterpret_cast<const short8*>(kmh + ((j0p + t4 * 16) << 5));
        SSTAGE(thrp, kprev, 0)
    }

    int j0c, thrc[4];
    SCAN(j0c, thrc)
    short8 kb[4];
    if (j0c >= 0) {
        #pragma unroll
        for (int t4 = 0; t4 < 4; ++t4)
            kb[t4] = *reinterpret_cast<const short8*>(kmh + ((j0c + t4 * 16) << 5));
    }

    int pb = 0;
    while (j0p >= 0) {
        const short8 v00 = *reinterpret_cast<const short8*>(vt0 + j0p);
        const short8 v01 = *reinterpret_cast<const short8*>(vt1 + j0p);
        const short8 v10 = *reinterpret_cast<const short8*>(vt0 + j0p + 32);
        const short8 v11 = *reinterpret_cast<const short8*>(vt1 + j0p + 32);

        if (j0c >= 0) SSTAGE(thrc, kb, pb ^ 1)

        int j0n, thrn[4];
        SCAN(j0n, thrn)
        short8 kn[4];
        if (j0n >= 0) {
            #pragma unroll
            for (int t4 = 0; t4 < 4; ++t4)
                kn[t4] = *reinterpret_cast<const short8*>(kmh + ((j0n + t4 * 16) << 5));
        }

        #pragma unroll
        for (int kt = 0; kt < 2; ++kt) {
            if (thrp[2 * kt] <= 0 && thrp[2 * kt + 1] <= 0) continue;
            const short8 b_p = *reinterpret_cast<const short8*>(
                &PTw[pb][l16][kt * 32 + quad * 8]);
            o_acc[0] = __builtin_amdgcn_mfma_f32_16x16x32_bf16(
                kt ? v10 : v00, b_p, o_acc[0], 0, 0, 0);
            o_acc[1] = __builtin_amdgcn_mfma_f32_16x16x32_bf16(
                kt ? v11 : v01, b_p, o_acc[1], 0, 0, 0);
        }

        j0p = j0c;
        #pragma unroll
        for (int t4 = 0; t4 < 4; ++t4) { thrp[t4] = thrc[t4]; kb[t4] = kn[t4]; thrc[t4] = thrn[t4]; }
        j0c = j0n;
        pb ^= 1;
    }
#undef SSTAGE
#undef SCAN

    // ---- epilogue: reuse this wave's smem region for O/l partials ----
    float (*obufw)[20] = reinterpret_cast<float(*)[20]>(smem[wv]);
    float* lbufw = reinterpret_cast<float*>(smem[wv] + 2560);

    l_acc += __shfl_xor(l_acc, 16);
    l_acc += __shfl_xor(l_acc, 32);
    if (lane < 16) lbufw[l16] = l_acc;
    #pragma unroll
    for (int tt = 0; tt < 2; ++tt)
        #pragma unroll
        for (int r = 0; r < 4; ++r)
            obufw[tt * 16 + quad * 4 + r][l16] = o_acc[tt][r];
    __syncthreads();

    const int q = tid & 15, d0 = (tid >> 4) * 2;
    float lt = 0.f, oa = 0.f, ob = 0.f;
    #pragma unroll
    for (int w = 0; w < 4; ++w) {
        const float (*obw)[20] = reinterpret_cast<const float(*)[20]>(smem[w]);
        lt += reinterpret_cast<const float*>(smem[w] + 2560)[q];
        oa += obw[d0][q];
        ob += obw[d0 + 1][q];
    }
    const float inv = RCP(lt);
    const unsigned int uo = pk_bf16(oa * inv, ob * inv);
    *reinterpret_cast<unsigned int*>(ao + (size_t)(nq0 + q) * 256 + h * 32 + d0) = uo;
}

// ---------------- 3) proj GEMM + bias, self-staging pw (unchanged) ----------------
__global__ __launch_bounds__(256) void k_proj(const unsigned short* __restrict__ ao,
                                              const float* __restrict__ pw,
                                              const float* __restrict__ pb,
                                              float* __restrict__ out) {
    __shared__ __align__(16) unsigned short Pt[64][264];
    const int tid = threadIdx.x;
    const int wave = tid >> 6, lane = tid & 63;
    const int l16 = lane & 15, quad = lane >> 4;
    const int n0 = blockIdx.x * 64;
    const int m0 = blockIdx.y * 64;

    {
        const int o_l = tid >> 2, cp = (tid & 3) * 64;
        const float4* wp = reinterpret_cast<const float4*>(pw + (size_t)(m0 + o_l) * 256 + cp);
        #pragma unroll
        for (int j = 0; j < 4; ++j) {
            const float4 g0 = wp[4 * j + 0], g1 = wp[4 * j + 1];
            const float4 g2 = wp[4 * j + 2], g3 = wp[4 * j + 3];
            unsigned int u[8];
            u[0] = pk_bf16(g0.x, g0.y); u[1] = pk_bf16(g0.z, g0.w);
            u[2] = pk_bf16(g1.x, g1.y); u[3] = pk_bf16(g1.z, g1.w);
            u[4] = pk_bf16(g2.x, g2.y); u[5] = pk_bf16(g2.z, g2.w);
            u[6] = pk_bf16(g3.x, g3.y); u[7] = pk_bf16(g3.z, g3.w);
            __builtin_memcpy(&Pt[o_l][cp + 16 * j], u, 32);
        }
    }
    __syncthreads();

    floatx4 acc[4] = {};
    #pragma unroll
    for (int cc = 0; cc < 8; ++cc) {
        const int c0 = cc * 32 + quad * 8;
        const short8 a = *reinterpret_cast<const short8*>(&Pt[wave * 16 + l16][c0]);
        #pragma unroll
        for (int t4 = 0; t4 < 4; ++t4) {
            const short8 b = *reinterpret_cast<const short8*>(
                ao + (size_t)(n0 + t4 * 16 + l16) * 256 + c0);
            acc[t4] = __builtin_amdgcn_mfma_f32_16x16x32_bf16(a, b, acc[t4], 0, 0, 0);
        }
    }
    #pragma unroll
    for (int t4 = 0; t4 < 4; ++t4) {
        #pragma unroll
        for (int r = 0; r < 4; ++r) {
            const int o = m0 + wave * 16 + quad * 4 + r;
            const int n = n0 + t4 * 16 + l16;
            out[(size_t)o * 4096 + n] = acc[t4][r] + pb[o];
        }
    }
}

extern "C" void kernel_launch(void* const* d_in, const int* in_sizes, int n_in,
                              void* d_out, int out_size, void* d_ws, size_t ws_size,
                              hipStream_t stream) {
    const float* x      = (const float*)d_in[0];
    const float* qkv_w  = (const float*)d_in[1];
    const float* proj_w = (const float*)d_in[2];
    const float* proj_b = (const float*)d_in[3];
    float* out = (float*)d_out;                    // [256,4096] fp32

    char* B = (char*)d_ws;
    const size_t MB = 1u << 20;
    unsigned short* ao = (unsigned short*)(B);
    unsigned short* qm = (unsigned short*)(B + 2 * MB);
    unsigned short* km = (unsigned short*)(B + 4 * MB);
    unsigned short* vt = (unsigned short*)(B + 6 * MB);

    k_qkv<<<dim3(64, 12), 256, 0, stream>>>(x, qkv_w, qm, km, vt);
    k_attn<<<dim3(2048), 256, 0, stream>>>(qm, km, vt, ao);
    k_proj<<<dim3(64, 4), 256, 0, stream>>>(ao, proj_w, proj_b, out);
}